// Round 8
// baseline (13.160 us; speedup 1.0000x reference)
//
#include <hip/hip_runtime.h>

// Attentionlayer: B=4, T=12, N=1024, F_IN=64, F_OUT=64.
//
// Identity (verified R0-R5, absmax 1.6e-2 vs threshold 1.5e-1):
//   sum(softmax(att, axis=3), axis=3) == 1 for every (b,t,n) row, so
//   res = leaky_relu(h * 1) = leaky_relu(x @ W).
//
// R7 = R6 with the compile fix: __builtin_nontemporal_* needs a NATIVE
// vector type (ext_vector_type), not HIP_vector_type<float,4>.
// R6 change recap: out-transpose tile uses the same [64][16]-float4 XOR
// swizzle as the x tile (was stride-68: 8-way write / 4-way read bank
// conflicts; any float4-aligned linear stride caps at 8 banks).
// Nontemporal hints on the once-touched x/out streams keep L2 clean.

typedef float f32x4 __attribute__((ext_vector_type(4)));

constexpr int K    = 64;             // F_IN
constexpr int C    = 64;             // F_OUT
constexpr int ROWS = 4 * 12 * 1024;  // 49152
constexpr int TR   = 64;             // rows per block
constexpr int NC   = 8;              // cols per wave (8 waves cover 64)
constexpr int BT   = 512;            // block threads

__global__ __launch_bounds__(BT) void gat_fused_kernel(
    const float* __restrict__ x, const float* __restrict__ W,
    float* __restrict__ out) {
  __shared__ f32x4 xt[TR * 16];      // swizzled x tile, 16 KB
  __shared__ f32x4 ot[TR * 16];      // swizzled out tile, 16 KB

  const int t    = threadIdx.x;
  const int lane = t & 63;  // row within tile
  const int wid  = t >> 6;  // wave id 0..7 -> 8-col slice
  const int c0   = __builtin_amdgcn_readfirstlane(wid * NC);
  const int row0 = (int)blockIdx.x * TR;

  // ---- Stage x tile (64x64 f32), XOR-swizzled; 512 thr x 2 f32x4 ----
  {
    const f32x4* src = reinterpret_cast<const f32x4*>(x + (size_t)row0 * K);
#pragma unroll
    for (int i = 0; i < 2; ++i) {
      int f = t + i * BT;                              // 0..1023
      f32x4 v = __builtin_nontemporal_load(src + f);   // coalesced 16B/lane
      int r = f >> 4, cch = f & 15;
      xt[r * 16 + (cch ^ (r & 15))] = v;
    }
  }
  __syncthreads();

  // ---- Compute: h[row][c0+j] = sum_k x[row][k] * W[k][c0+j] ----
  float acc[NC];
#pragma unroll
  for (int j = 0; j < NC; ++j) acc[j] = 0.f;

#pragma unroll
  for (int kq = 0; kq < 16; ++kq) {
    f32x4 xv = xt[lane * 16 + (kq ^ (lane & 15))];  // own row, <=2-way
    const float* wr = W + (kq * 4) * C + c0;        // wave-uniform -> s_load
#pragma unroll
    for (int q = 0; q < 4; ++q) {
      const float* wk = wr + q * C;
      float xq = xv[q];
#pragma unroll
      for (int j = 0; j < NC; ++j)
        acc[j] = fmaf(xq, wk[j], acc[j]);  // v_fmac, SGPR W operand
    }
  }

  // ---- leaky_relu + swizzled transpose write (no extra barrier) ----
  // Lane owns row 'lane'; writes its NC/4=2 f32x4 chunks at slots
  // (c0/4+q) ^ (lane&15): bank-group spread over all 8 -> <=2-way.
#pragma unroll
  for (int q = 0; q < NC / 4; ++q) {
    float a0 = acc[4 * q + 0], a1 = acc[4 * q + 1];
    float a2 = acc[4 * q + 2], a3 = acc[4 * q + 3];
    f32x4 v;
    v[0] = a0 > 0.f ? a0 : 0.01f * a0;
    v[1] = a1 > 0.f ? a1 : 0.01f * a1;
    v[2] = a2 > 0.f ? a2 : 0.01f * a2;
    v[3] = a3 > 0.f ? a3 : 0.01f * a3;
    int cq = (c0 >> 2) + q;
    ot[lane * 16 + (cq ^ (lane & 15))] = v;
  }
  __syncthreads();

  // ---- Coalesced nontemporal f32x4 stores of the transposed tile ----
  f32x4* gdst = reinterpret_cast<f32x4*>(out + (size_t)row0 * C);
#pragma unroll
  for (int i = 0; i < 2; ++i) {
    int f = t + i * BT;
    int r = f >> 4, cch = f & 15;
    __builtin_nontemporal_store(ot[r * 16 + (cch ^ (r & 15))], gdst + f);
  }
}

extern "C" void kernel_launch(void* const* d_in, const int* in_sizes, int n_in,
                              void* d_out, int out_size, void* d_ws, size_t ws_size,
                              hipStream_t stream) {
  // setup_inputs order: x, adj, W, a. Only x and W matter (see identity).
  const float* x = (const float*)d_in[0];
  const float* W = (const float*)d_in[2];
  float* out     = (float*)d_out;

  dim3 grid(ROWS / TR);  // 768 blocks, 3 blocks/CU exactly
  dim3 block(BT);
  gat_fused_kernel<<<grid, block, 0, stream>>>(x, W, out);
}